// Round 3
// baseline (184.313 us; speedup 1.0000x reference)
//
#include <hip/hip_runtime.h>
#include <hip/hip_bf16.h>
#include <math.h>
#include <stdint.h>

#define B_ 64
#define L_ 2048
#define H_ 128
#define O_ 128
#define N_ 256
#define CH_ 128      // timesteps per chunk
#define NCH_ 16      // chunks
#define SPC_ 8       // strips (16 t) per chunk

using f32x4 = __attribute__((ext_vector_type(4))) float;
using i32x4 = __attribute__((ext_vector_type(4))) int;
using i32x2 = __attribute__((ext_vector_type(2))) int;
using h16x8 = __attribute__((ext_vector_type(8))) _Float16;

__device__ __forceinline__ unsigned short f16_bits(float v) {
    _Float16 h = (_Float16)v;                 // RNE convert
    return __builtin_bit_cast(unsigned short, h);
}
__device__ __forceinline__ int pack_f16(float a, float b) {
    return (int)((unsigned)f16_bits(a) | ((unsigned)f16_bits(b) << 16));
}
__device__ __forceinline__ float2 cmul(float2 a, float2 b) {
    return make_float2(a.x * b.x - a.y * b.y, a.x * b.y + a.y * b.x);
}

// ---------------------------------------------------------------------------
// prep: every block self-computes the nu-sorted permutation (rank 0 = slowest
// decay), then fills its slice of: B2Tr (fp16 (gamma*B)^T, rank-ordered cols),
// lamjR[rank][j]=lam^(15-j), lam16R=lam^16, lamCCr[c][rank]=lam^(128*(15-c)),
// nuR, perm, and zeroes X.
// ---------------------------------------------------------------------------
__global__ void prep_kernel(const float* __restrict__ nu_log, const float* __restrict__ theta_log,
                            const float* __restrict__ gamma_log, const float* __restrict__ B_re,
                            const float* __restrict__ B_im, unsigned short* __restrict__ B2Tr,
                            float2* __restrict__ lamjR, float2* __restrict__ lam16R,
                            float2* __restrict__ lamCCr, float* __restrict__ nuR,
                            int* __restrict__ perm, float* __restrict__ X) {
    __shared__ float nu_s[N_];
    __shared__ int perm_s[N_];
    const int t = threadIdx.x;
    float nu = expf(nu_log[t]);
    nu_s[t] = nu;
    __syncthreads();
    {
        int rank = 0;
        for (int j = 0; j < N_; ++j) {
            float vj = nu_s[j];
            rank += (vj < nu || (vj == nu && j < t)) ? 1 : 0;
        }
        perm_s[rank] = t;
    }
    __syncthreads();
    const int bb = blockIdx.x;
    if (bb < 64) {
        #pragma unroll
        for (int kk = 0; kk < 4; ++kk) {
            int e = bb * 1024 + kk * 256 + t;       // 0..65535
            int part = e >> 15, rank = (e >> 7) & 255, h = e & 127;
            int n = perm_s[rank];
            float g = expf(gamma_log[n]);
            float v = (part ? B_im : B_re)[n * H_ + h] * g;
            B2Tr[e] = f16_bits(v);
        }
    } else if (bb == 64) {
        int r = t, n = perm_s[r];
        float nun = nu_s[n];
        double th = (double)expf(theta_log[n]);
        double rr = exp(-(double)nun);
        double sn, cs;
        sincos(th, &sn, &cs);
        double lre = rr * cs, lim = rr * sn;
        double pre = 1.0, pim = 0.0;
        for (int k = 0; k < 16; ++k) {
            lamjR[r * 16 + 15 - k] = make_float2((float)pre, (float)pim);
            double t1 = pre * lre - pim * lim, t2 = pre * lim + pim * lre;
            pre = t1; pim = t2;
        }
        lam16R[r] = make_float2((float)pre, (float)pim);   // lam^16
        nuR[r] = nun;
        perm[r] = n;
        double wre = pre, wim = pim;                        // -> lam^128
        for (int i = 0; i < 3; ++i) {
            double a = wre * wre - wim * wim, b2 = 2.0 * wre * wim;
            wre = a; wim = b2;
        }
        double are = 1.0, aim = 0.0;
        for (int c = 15; c >= 0; --c) {
            lamCCr[c * N_ + r] = make_float2((float)are, (float)aim);
            double a = are * wre - aim * wim, b2 = are * wim + aim * wre;
            are = a; aim = b2;
        }
    } else {
        int idx = (bb - 65) * 1024 + t * 4;                 // 32 blocks x 1024 floats
        f32x4 z = {0.f, 0.f, 0.f, 0.f};
        *(f32x4*)&X[idx] = z;
    }
}

// ---------------------------------------------------------------------------
// scan: block = (chunk c, b), 512 threads = 8 waves.
// Round-3 change: WORK-QUEUE strip distribution. The strip recurrence
// z <- lam^16 z + A_s is associative, so a sub-range [s0,s1) of a pair's
// strips is an independent item: its partial sum only needs an extra
// rotation by lam16^(SPC-s1) in the epilogue. All alive (pair,strip) items
// of the block are flattened (T total) and wave g takes the contiguous
// slice [g*T/8,(g+1)*T/8) -- perfect +/-1 intra-block balance regardless of
// the nu distribution. (Round-2's static {g,15-g} pair map still left wave
// imbalance: pair 0 alone is ~128 strips, 3x the per-wave mean, and per-CU
// c-sets {k,k+4,k+8,k+12} ranged 52..141 strips -> straggler tail at serial
// latency was the remaining ~15 us.) Early chunks now split pair 0's 8
// strips one-per-wave: block critical path 8 strips -> 1.
// Phase 1 (instruction-coalesced): instruction k covers a contiguous 1 KB per
// wave (lane i <- base + i*16B). Pack to fp16, XOR-swizzled LDS image
// (unit = (c4>>1) ^ (r&15)), one barrier. Queue gates (16 uniform nuR loads
// + ceilf) computed between load-issue and pack so latency hides.
// ---------------------------------------------------------------------------
__global__ __launch_bounds__(512, 4)
void scan_kernel(const float* __restrict__ u, const unsigned short* __restrict__ B2Tr,
                 const float2* __restrict__ lamjR, const float2* __restrict__ lam16R,
                 const float2* __restrict__ lamCCr, const float* __restrict__ nuR,
                 const int* __restrict__ perm, float* __restrict__ X) {
    const int bx = blockIdx.x;
    const int c = bx >> 6;            // chunk 0..15 — each c spread over XCDs
    const int b = bx & 63;
    const int tid = threadIdx.x;

    __shared__ __align__(16) unsigned short Asm[CH_ * H_];   // 32 KB fp16 chunk image

    // ---- phase 1: issue chunk loads (contiguous 1 KB per wave instruction) ----
    const float* gsrc = u + ((size_t)b * L_ + (size_t)(c * CH_)) * H_;
    f32x4 Lv[8];
    #pragma unroll
    for (int k = 0; k < 8; ++k)
        Lv[k] = *(const f32x4*)(gsrc + k * 2048 + tid * 4);

    // ---- queue setup (uniform, hides under load latency + barrier) ----
    const int g = tid >> 6;                // wave 0..7
    const int lane = tid & 63;
    const int m = lane & 15, q = lane >> 4;
    // strip alive iff nu*(base_e - 16s) <= 35  (e^-35 ~ 6e-16 truncation)
    const float base_e = 2032.0f - 128.0f * (float)c;
    int T = 0;
    #pragma unroll
    for (int p = 0; p < 16; ++p) {
        float nu = nuR[p * 16];
        int sp = (int)ceilf((base_e - 35.0f / nu) * 0.0625f);
        sp = sp < 0 ? 0 : (sp > SPC_ ? SPC_ : sp);
        T += SPC_ - sp;
    }
    const int i0 = (g * T) >> 3;           // this wave's flat item range
    const int i1 = ((g + 1) * T) >> 3;

    // ---- phase 1 cont.: pack + swizzled LDS store ----
    {
        const int c4 = tid & 31;            // 4-float granule within row
        const int gg = c4 >> 1;             // 8-float group 0..15
        const int half = c4 & 1;
        #pragma unroll
        for (int k = 0; k < 8; ++k) {
            const int r = k * 16 + (tid >> 5);                    // row 0..127
            i32x2 w;
            w[0] = pack_f16(Lv[k][0], Lv[k][1]);
            w[1] = pack_f16(Lv[k][2], Lv[k][3]);
            *(i32x2*)&Asm[r * H_ + ((gg ^ (r & 15)) * 8) + half * 4] = w;
        }
    }
    __syncthreads();

    // ---- phase 2: walk this wave's queue slice (not unrolled: big body) ----
    int pre = 0;
    for (int p = 0; p < 16; ++p) {
        if (pre >= i1) break;
        float nu = nuR[p * 16];
        int sp = (int)ceilf((base_e - 35.0f / nu) * 0.0625f);
        sp = sp < 0 ? 0 : (sp > SPC_ ? SPC_ : sp);
        const int len = SPC_ - sp;
        const int a0 = i0 - pre;
        const int a1 = i1 - pre;
        pre += len;
        const int aa = a0 < 0 ? 0 : a0;
        const int bb2 = a1 < len ? a1 : len;
        if (aa >= bb2) continue;           // wave-uniform skip
        const int s0 = sp + aa, s1 = sp + bb2;   // absolute strip range [s0,s1)
        const int rank = p * 16 + m;

        h16x8 bfr[2][4];
        #pragma unroll
        for (int part = 0; part < 2; ++part) {
            const unsigned short* rp = B2Tr + (size_t)(part * N_ + rank) * H_ + q * 8;
            #pragma unroll
            for (int sl = 0; sl < 4; ++sl)
                bfr[part][sl] = *(const h16x8*)(rp + sl * 32);
        }
        float2 wl[4];
        #pragma unroll
        for (int r2 = 0; r2 < 4; ++r2) wl[r2] = lamjR[rank * 16 + q * 4 + r2];
        const float2 l16 = lam16R[rank];

        float2 zre = make_float2(0.f, 0.f), zim = make_float2(0.f, 0.f);
        for (int s = s0; s < s1; ++s) {
            const int row = s * 16 + m;
            h16x8 afr[4];
            #pragma unroll
            for (int sl = 0; sl < 4; ++sl) {
                const int unit = (sl * 4 + q) ^ m;
                afr[sl] = *(const h16x8*)&Asm[row * H_ + unit * 8];
            }
            // rescale accumulators by lam^16
            float2 t0 = zre;
            zre.x = l16.x * t0.x - l16.y * t0.y;
            zre.y = l16.x * t0.y + l16.y * t0.x;
            float2 t1 = zim;
            zim.x = l16.x * t1.x - l16.y * t1.y;
            zim.y = l16.x * t1.y + l16.y * t1.x;
            f32x4 acc = {0.f, 0.f, 0.f, 0.f};
            #pragma unroll
            for (int sl = 0; sl < 4; ++sl)
                acc = __builtin_amdgcn_mfma_f32_16x16x32_f16(afr[sl], bfr[0][sl], acc, 0, 0, 0);
            #pragma unroll
            for (int r2 = 0; r2 < 4; ++r2) {
                zre.x += wl[r2].x * acc[r2];
                zre.y += wl[r2].y * acc[r2];
            }
            f32x4 acc2 = {0.f, 0.f, 0.f, 0.f};
            #pragma unroll
            for (int sl = 0; sl < 4; ++sl)
                acc2 = __builtin_amdgcn_mfma_f32_16x16x32_f16(afr[sl], bfr[1][sl], acc2, 0, 0, 0);
            #pragma unroll
            for (int r2 = 0; r2 < 4; ++r2) {
                zim.x += wl[r2].x * acc2[r2];
                zim.y += wl[r2].y * acc2[r2];
            }
        }

        // reduce over q, rotate by lam16^(SPC-s1) * lamCC, atomic partials
        float a = zre.x, b2 = zre.y, c2 = zim.x, d2 = zim.y;
        a  += __shfl_xor(a, 16);  a  += __shfl_xor(a, 32);
        b2 += __shfl_xor(b2, 16); b2 += __shfl_xor(b2, 32);
        c2 += __shfl_xor(c2, 16); c2 += __shfl_xor(c2, 32);
        d2 += __shfl_xor(d2, 16); d2 += __shfl_xor(d2, 32);
        if (lane < 16) {
            const int n = perm[rank];
            float2 lc = lamCCr[c * N_ + rank];
            // lc *= lam16^(SPC - s1)   (aligns sub-range end to chunk end)
            int e = SPC_ - s1;                 // 0..7, wave-uniform
            float2 pw = l16;
            while (e) {
                if (e & 1) lc = cmul(lc, pw);
                e >>= 1;
                if (e) pw = cmul(pw, pw);
            }
            float prr = lc.x * a - lc.y * b2;
            float pri = lc.x * b2 + lc.y * a;
            float pir = lc.x * c2 - lc.y * d2;
            float pii = lc.x * d2 + lc.y * c2;
            atomicAdd(&X[(size_t)(b * N_ + n) * 2 + 0], prr - pii);
            atomicAdd(&X[(size_t)(b * N_ + n) * 2 + 1], pri + pir);
        }
    }
}

// ---------------------------------------------------------------------------
// out: y[b,o] = sum_n (Cre*Xre - Cim*Xim) + sum_h D[o,h]*u[b,L-1,h]
// ---------------------------------------------------------------------------
__global__ void out_kernel(const float* __restrict__ X, const float* __restrict__ C_re,
                           const float* __restrict__ C_im, const float* __restrict__ Dm,
                           const float* __restrict__ u, float* __restrict__ out) {
    __shared__ float xre[N_], xim[N_], ul[H_];
    const int b = blockIdx.x;
    const int t = threadIdx.x;
    xre[t] = X[(size_t)(b * N_ + t) * 2 + 0];
    xim[t] = X[(size_t)(b * N_ + t) * 2 + 1];
    if (t < H_) ul[t] = u[((size_t)b * L_ + (L_ - 1)) * H_ + t];
    __syncthreads();
    const int o = t >> 1;
    const int h = t & 1;
    const float* cre = C_re + o * N_ + h * 128;
    const float* cim = C_im + o * N_ + h * 128;
    const float* xr = xre + h * 128;
    const float* xi = xim + h * 128;
    float s = 0.f;
    #pragma unroll 4
    for (int n = 0; n < 128; ++n) s += cre[n] * xr[n] - cim[n] * xi[n];
    const float* dp = Dm + o * H_ + h * 64;
    const float* up = ul + h * 64;
    #pragma unroll 4
    for (int k = 0; k < 64; ++k) s += dp[k] * up[k];
    s += __shfl_xor(s, 1);
    if (h == 0) out[b * O_ + o] = s;
}

extern "C" void kernel_launch(void* const* d_in, const int* in_sizes, int n_in,
                              void* d_out, int out_size, void* d_ws, size_t ws_size,
                              hipStream_t stream) {
    const float* u         = (const float*)d_in[2];   // dynamics_disturbance_time_window
    const float* nu_log    = (const float*)d_in[3];
    const float* theta_log = (const float*)d_in[4];
    const float* gamma_log = (const float*)d_in[5];
    const float* B_re      = (const float*)d_in[6];
    const float* B_im      = (const float*)d_in[7];
    const float* C_re      = (const float*)d_in[8];
    const float* C_im      = (const float*)d_in[9];
    const float* Dm        = (const float*)d_in[10];

    char* ws = (char*)d_ws;
    float*          X      = (float*)ws;                       // 131072 B
    unsigned short* B2Tr   = (unsigned short*)(ws + 131072);   // 131072 B
    float2*         lamjR  = (float2*)(ws + 262144);           // 32768 B
    float2*         lam16R = (float2*)(ws + 294912);           // 2048 B
    float2*         lamCCr = (float2*)(ws + 296960);           // 32768 B
    float*          nuR    = (float*)(ws + 329728);            // 1024 B
    int*            perm   = (int*)(ws + 330752);              // 1024 B

    prep_kernel<<<97, 256, 0, stream>>>(nu_log, theta_log, gamma_log, B_re, B_im,
                                        B2Tr, lamjR, lam16R, lamCCr, nuR, perm, X);
    scan_kernel<<<B_ * NCH_, 512, 0, stream>>>(u, B2Tr, lamjR, lam16R, lamCCr, nuR, perm, X);
    out_kernel<<<B_, 256, 0, stream>>>(X, C_re, C_im, Dm, u, (float*)d_out);
}

// Round 4
// 172.493 us; speedup vs baseline: 1.0685x; 1.0685x over previous
//
#include <hip/hip_runtime.h>
#include <hip/hip_bf16.h>
#include <math.h>
#include <stdint.h>

#define B_ 64
#define L_ 2048
#define H_ 128
#define O_ 128
#define N_ 256
#define CH_ 128      // timesteps per chunk
#define NCH_ 16      // chunks
#define SPC_ 8       // strips (16 t) per chunk

using f32x4 = __attribute__((ext_vector_type(4))) float;
using i32x4 = __attribute__((ext_vector_type(4))) int;
using i32x2 = __attribute__((ext_vector_type(2))) int;
using h16x8 = __attribute__((ext_vector_type(8))) _Float16;

__device__ __forceinline__ unsigned short f16_bits(float v) {
    _Float16 h = (_Float16)v;                 // RNE convert
    return __builtin_bit_cast(unsigned short, h);
}
__device__ __forceinline__ int pack_f16(float a, float b) {
    return (int)((unsigned)f16_bits(a) | ((unsigned)f16_bits(b) << 16));
}

// ---------------------------------------------------------------------------
// prep: every block self-computes the nu-sorted permutation (rank 0 = slowest
// decay), then fills its slice of: B2Tr (fp16 (gamma*B)^T, rank-ordered cols),
// lamjR[rank][j]=lam^(15-j), lam16R=lam^16, lamCCr[c][rank]=lam^(128*(15-c)),
// nuR, perm, and zeroes X.
// ---------------------------------------------------------------------------
__global__ void prep_kernel(const float* __restrict__ nu_log, const float* __restrict__ theta_log,
                            const float* __restrict__ gamma_log, const float* __restrict__ B_re,
                            const float* __restrict__ B_im, unsigned short* __restrict__ B2Tr,
                            float2* __restrict__ lamjR, float2* __restrict__ lam16R,
                            float2* __restrict__ lamCCr, float* __restrict__ nuR,
                            int* __restrict__ perm, float* __restrict__ X) {
    __shared__ float nu_s[N_];
    __shared__ int perm_s[N_];
    const int t = threadIdx.x;
    float nu = expf(nu_log[t]);
    nu_s[t] = nu;
    __syncthreads();
    {
        int rank = 0;
        for (int j = 0; j < N_; ++j) {
            float vj = nu_s[j];
            rank += (vj < nu || (vj == nu && j < t)) ? 1 : 0;
        }
        perm_s[rank] = t;
    }
    __syncthreads();
    const int bb = blockIdx.x;
    if (bb < 64) {
        #pragma unroll
        for (int kk = 0; kk < 4; ++kk) {
            int e = bb * 1024 + kk * 256 + t;       // 0..65535
            int part = e >> 15, rank = (e >> 7) & 255, h = e & 127;
            int n = perm_s[rank];
            float g = expf(gamma_log[n]);
            float v = (part ? B_im : B_re)[n * H_ + h] * g;
            B2Tr[e] = f16_bits(v);
        }
    } else if (bb == 64) {
        int r = t, n = perm_s[r];
        float nun = nu_s[n];
        double th = (double)expf(theta_log[n]);
        double rr = exp(-(double)nun);
        double sn, cs;
        sincos(th, &sn, &cs);
        double lre = rr * cs, lim = rr * sn;
        double pre = 1.0, pim = 0.0;
        for (int k = 0; k < 16; ++k) {
            lamjR[r * 16 + 15 - k] = make_float2((float)pre, (float)pim);
            double t1 = pre * lre - pim * lim, t2 = pre * lim + pim * lre;
            pre = t1; pim = t2;
        }
        lam16R[r] = make_float2((float)pre, (float)pim);   // lam^16
        nuR[r] = nun;
        perm[r] = n;
        double wre = pre, wim = pim;                        // -> lam^128
        for (int i = 0; i < 3; ++i) {
            double a = wre * wre - wim * wim, b2 = 2.0 * wre * wim;
            wre = a; wim = b2;
        }
        double are = 1.0, aim = 0.0;
        for (int c = 15; c >= 0; --c) {
            lamCCr[c * N_ + r] = make_float2((float)are, (float)aim);
            double a = are * wre - aim * wim, b2 = are * wim + aim * wre;
            are = a; aim = b2;
        }
    } else {
        int idx = (bb - 65) * 1024 + t * 4;                 // 32 blocks x 1024 floats
        f32x4 z = {0.f, 0.f, 0.f, 0.f};
        *(f32x4*)&X[idx] = z;
    }
}

// ---------------------------------------------------------------------------
// scan: block = (chunk c, b), 512 threads = 8 waves.  (round-2 structure —
// best measured at ~31.5 us; round-3's per-strip work queue REGRESSED +8.5 us
// from doubled gate-walk VALU, per-wave bfr/epilogue/atomic overhead, and
// worse codegen, so it was reverted.)
//  (a) bx = c*64 + b: spreads each chunk's 64 blocks across the 8 XCDs
//      (bx%8 = b%8), so the heavy c=15 blocks don't pile on one XCD.
//  (b) wave g owns pairs {g, 15-g}: at hot chunks (c>=13) pairs 0..8 are all
//      ~8 strips, so waves are ~balanced; cold chunks leave idle waves but
//      those blocks are cheap (~8 strips total).
//  (c) nuR loads + strip-window computation hoisted above __syncthreads so
//      the live/dead branch latency hides under the barrier wait.
// Phase 1 (instruction-coalesced): instruction k covers a contiguous 1 KB per
// wave (lane i <- base + i*16B); every 64-B line is consumed by 4 lanes of
// the SAME instruction. Pack to fp16, XOR-swizzled LDS image
// (unit = (c4>>1) ^ (r&15)), one barrier.
// Phase 2: per pair: z <- lam^16 z + sum_j lam^(15-j) Bu_j per strip, strips
// below the decay window skipped. Epilogue rotates by lamCC and atomicAdds
// complex x[b,n].
// ---------------------------------------------------------------------------
__global__ __launch_bounds__(512, 4)
void scan_kernel(const float* __restrict__ u, const unsigned short* __restrict__ B2Tr,
                 const float2* __restrict__ lamjR, const float2* __restrict__ lam16R,
                 const float2* __restrict__ lamCCr, const float* __restrict__ nuR,
                 const int* __restrict__ perm, float* __restrict__ X) {
    const int bx = blockIdx.x;
    const int c = bx >> 6;            // chunk 0..15 — each c spread over XCDs
    const int b = bx & 63;
    const int tid = threadIdx.x;

    __shared__ __align__(16) unsigned short Asm[CH_ * H_];   // 32 KB fp16 chunk image

    // ---- phase 1: issue chunk loads (contiguous 1 KB per wave instruction) ----
    const float* gsrc = u + ((size_t)b * L_ + (size_t)(c * CH_)) * H_;
    f32x4 Lv[8];
    #pragma unroll
    for (int k = 0; k < 8; ++k)
        Lv[k] = *(const f32x4*)(gsrc + k * 2048 + tid * 4);

    // ---- hoisted phase-2 setup: overlaps load latency + barrier ----
    const int g = tid >> 6;                // wave 0..7
    const int lane = tid & 63;
    const int m = lane & 15, q = lane >> 4;
    const int p0 = g, p1 = 15 - g;         // balanced pair assignment
    // strip alive iff nu*(base_e - 16s) <= 35  (e^-35 ~ 6e-16 truncation)
    const float base_e = 2032.0f - 128.0f * (float)c;
    const float nu0 = nuR[p0 * 16];
    const float nu1 = nuR[p1 * 16];
    int spA = (int)ceilf((base_e - 35.0f / nu0) * 0.0625f);
    if (spA < 0) spA = 0;
    int spB = (int)ceilf((base_e - 35.0f / nu1) * 0.0625f);
    if (spB < 0) spB = 0;

    // ---- phase 1 cont.: pack + swizzled LDS store ----
    {
        const int c4 = tid & 31;            // 4-float granule within row
        const int gg = c4 >> 1;             // 8-float group 0..15
        const int half = c4 & 1;
        #pragma unroll
        for (int k = 0; k < 8; ++k) {
            const int r = k * 16 + (tid >> 5);                    // row 0..127
            i32x2 w;
            w[0] = pack_f16(Lv[k][0], Lv[k][1]);
            w[1] = pack_f16(Lv[k][2], Lv[k][3]);
            *(i32x2*)&Asm[r * H_ + ((gg ^ (r & 15)) * 8) + half * 4] = w;
        }
    }
    __syncthreads();

    // ---- phase 2: per-wave MFMA from LDS ----
    if (spA < SPC_) {                      // wave has live work (spA <= spB)
        #pragma unroll
        for (int p = 0; p < 2; ++p) {
            const int sp = p ? spB : spA;
            if (sp >= SPC_) continue;      // pair dead (wave-uniform)
            const int pp = p ? p1 : p0;
            const int rank = pp * 16 + m;

            h16x8 bfr[2][4];
            #pragma unroll
            for (int part = 0; part < 2; ++part) {
                const unsigned short* rp = B2Tr + (size_t)(part * N_ + rank) * H_ + q * 8;
                #pragma unroll
                for (int sl = 0; sl < 4; ++sl)
                    bfr[part][sl] = *(const h16x8*)(rp + sl * 32);
            }
            float2 wl[4];
            #pragma unroll
            for (int r2 = 0; r2 < 4; ++r2) wl[r2] = lamjR[rank * 16 + q * 4 + r2];
            const float2 l16 = lam16R[rank];

            float2 zre = make_float2(0.f, 0.f), zim = make_float2(0.f, 0.f);
            for (int s = sp; s < SPC_; ++s) {
                const int row = s * 16 + m;
                h16x8 afr[4];
                #pragma unroll
                for (int sl = 0; sl < 4; ++sl) {
                    const int unit = (sl * 4 + q) ^ m;
                    afr[sl] = *(const h16x8*)&Asm[row * H_ + unit * 8];
                }
                // rescale accumulators by lam^16
                float2 t0 = zre;
                zre.x = l16.x * t0.x - l16.y * t0.y;
                zre.y = l16.x * t0.y + l16.y * t0.x;
                float2 t1 = zim;
                zim.x = l16.x * t1.x - l16.y * t1.y;
                zim.y = l16.x * t1.y + l16.y * t1.x;
                f32x4 acc = {0.f, 0.f, 0.f, 0.f};
                #pragma unroll
                for (int sl = 0; sl < 4; ++sl)
                    acc = __builtin_amdgcn_mfma_f32_16x16x32_f16(afr[sl], bfr[0][sl], acc, 0, 0, 0);
                #pragma unroll
                for (int r2 = 0; r2 < 4; ++r2) {
                    zre.x += wl[r2].x * acc[r2];
                    zre.y += wl[r2].y * acc[r2];
                }
                f32x4 acc2 = {0.f, 0.f, 0.f, 0.f};
                #pragma unroll
                for (int sl = 0; sl < 4; ++sl)
                    acc2 = __builtin_amdgcn_mfma_f32_16x16x32_f16(afr[sl], bfr[1][sl], acc2, 0, 0, 0);
                #pragma unroll
                for (int r2 = 0; r2 < 4; ++r2) {
                    zim.x += wl[r2].x * acc2[r2];
                    zim.y += wl[r2].y * acc2[r2];
                }
            }

            // reduce over q, rotate by lamCC, atomic complex partials
            float a = zre.x, b2 = zre.y, c2 = zim.x, d2 = zim.y;
            a  += __shfl_xor(a, 16);  a  += __shfl_xor(a, 32);
            b2 += __shfl_xor(b2, 16); b2 += __shfl_xor(b2, 32);
            c2 += __shfl_xor(c2, 16); c2 += __shfl_xor(c2, 32);
            d2 += __shfl_xor(d2, 16); d2 += __shfl_xor(d2, 32);
            if (lane < 16) {
                const int n = perm[rank];
                float2 lc = lamCCr[c * N_ + rank];
                float prr = lc.x * a - lc.y * b2;
                float pri = lc.x * b2 + lc.y * a;
                float pir = lc.x * c2 - lc.y * d2;
                float pii = lc.x * d2 + lc.y * c2;
                atomicAdd(&X[(size_t)(b * N_ + n) * 2 + 0], prr - pii);
                atomicAdd(&X[(size_t)(b * N_ + n) * 2 + 1], pri + pir);
            }
        }
    }
}

// ---------------------------------------------------------------------------
// out: y[b,o] = sum_n (Cre*Xre - Cim*Xim) + sum_h D[o,h]*u[b,L-1,h]
// Round-4 rewrite: the old version (256 threads, 1 serial scalar 128+64-iter
// dot per 2 threads) measured 14.9 us at 1.7% occupancy — pure latency bound.
// Now: 512 threads, 4 threads per o; each thread does 64 n + 32 h with f32x4
// loads (24 vector loads of MLP per thread), then __shfl_xor(1,2) reduce.
// X staged coalesced as float2; LDS 16B-aligned for vector reads.
// ---------------------------------------------------------------------------
__global__ __launch_bounds__(512)
void out_kernel(const float* __restrict__ X, const float* __restrict__ C_re,
                const float* __restrict__ C_im, const float* __restrict__ Dm,
                const float* __restrict__ u, float* __restrict__ out) {
    __shared__ __align__(16) float xre[N_];
    __shared__ __align__(16) float xim[N_];
    __shared__ __align__(16) float ul[H_];
    const int b = blockIdx.x;
    const int t = threadIdx.x;
    if (t < N_) {
        float2 x2 = *(const float2*)&X[(size_t)(b * N_ + t) * 2];
        xre[t] = x2.x;
        xim[t] = x2.y;
    }
    if (t < H_) ul[t] = u[((size_t)b * L_ + (L_ - 1)) * H_ + t];
    __syncthreads();
    const int o = t >> 2;              // 128 outputs
    const int part = t & 3;            // quarter of the reduction
    const float* cre = C_re + o * N_ + part * 64;
    const float* cim = C_im + o * N_ + part * 64;
    const float* xr  = xre + part * 64;
    const float* xi  = xim + part * 64;
    float s = 0.f;
    #pragma unroll
    for (int i = 0; i < 16; ++i) {
        f32x4 cr = *(const f32x4*)(cre + i * 4);
        f32x4 ci = *(const f32x4*)(cim + i * 4);
        f32x4 vr = *(const f32x4*)(xr + i * 4);
        f32x4 vi = *(const f32x4*)(xi + i * 4);
        s += cr[0] * vr[0] - ci[0] * vi[0];
        s += cr[1] * vr[1] - ci[1] * vi[1];
        s += cr[2] * vr[2] - ci[2] * vi[2];
        s += cr[3] * vr[3] - ci[3] * vi[3];
    }
    const float* dp = Dm + o * H_ + part * 32;
    const float* up = ul + part * 32;
    #pragma unroll
    for (int i = 0; i < 8; ++i) {
        f32x4 d4 = *(const f32x4*)(dp + i * 4);
        f32x4 u4 = *(const f32x4*)(up + i * 4);
        s += d4[0] * u4[0] + d4[1] * u4[1] + d4[2] * u4[2] + d4[3] * u4[3];
    }
    s += __shfl_xor(s, 1);
    s += __shfl_xor(s, 2);
    if (part == 0) out[b * O_ + o] = s;
}

extern "C" void kernel_launch(void* const* d_in, const int* in_sizes, int n_in,
                              void* d_out, int out_size, void* d_ws, size_t ws_size,
                              hipStream_t stream) {
    const float* u         = (const float*)d_in[2];   // dynamics_disturbance_time_window
    const float* nu_log    = (const float*)d_in[3];
    const float* theta_log = (const float*)d_in[4];
    const float* gamma_log = (const float*)d_in[5];
    const float* B_re      = (const float*)d_in[6];
    const float* B_im      = (const float*)d_in[7];
    const float* C_re      = (const float*)d_in[8];
    const float* C_im      = (const float*)d_in[9];
    const float* Dm        = (const float*)d_in[10];

    char* ws = (char*)d_ws;
    float*          X      = (float*)ws;                       // 131072 B
    unsigned short* B2Tr   = (unsigned short*)(ws + 131072);   // 131072 B
    float2*         lamjR  = (float2*)(ws + 262144);           // 32768 B
    float2*         lam16R = (float2*)(ws + 294912);           // 2048 B
    float2*         lamCCr = (float2*)(ws + 296960);           // 32768 B
    float*          nuR    = (float*)(ws + 329728);            // 1024 B
    int*            perm   = (int*)(ws + 330752);              // 1024 B

    prep_kernel<<<97, 256, 0, stream>>>(nu_log, theta_log, gamma_log, B_re, B_im,
                                        B2Tr, lamjR, lam16R, lamCCr, nuR, perm, X);
    scan_kernel<<<B_ * NCH_, 512, 0, stream>>>(u, B2Tr, lamjR, lam16R, lamCCr, nuR, perm, X);
    out_kernel<<<B_, 512, 0, stream>>>(X, C_re, C_im, Dm, u, (float*)d_out);
}